// Round 1
// baseline (1618.308 us; speedup 1.0000x reference)
//
#include <hip/hip_runtime.h>
#include <stdint.h>
#include <stddef.h>

#define BB 8
#define TENC 200
#define UU 100
#define UP1 101
#define VP1 1025
#define ED 128
#define PD 512

typedef __attribute__((ext_vector_type(8))) unsigned short ushort8;
typedef __attribute__((ext_vector_type(8))) __bf16 bf16x8;
typedef __attribute__((ext_vector_type(4))) float f32x4;

__device__ __forceinline__ float bf2f(unsigned short u){
  unsigned int x = ((unsigned int)u) << 16;
  return __builtin_bit_cast(float, x);
}
__device__ __forceinline__ unsigned short f2bf(float f){
  unsigned int x = __builtin_bit_cast(unsigned int, f);
  unsigned int r = (x + 0x7fffu + ((x >> 16) & 1u)) >> 16;
  return (unsigned short)r;
}
__device__ __forceinline__ float tanh_fast(float x){
  float e = __expf(2.0f * x);
  return 1.0f - 2.0f / (e + 1.0f);
}
__device__ __forceinline__ float sigm(float x){
  return 1.0f / (1.0f + __expf(-x));
}

// ---------------- fp32 -> bf16 convert (for W_joint) ----------------
__global__ __launch_bounds__(256) void k_cvt_bf16(const float* __restrict__ src,
                                                  unsigned short* __restrict__ dst, int n){
  int i = blockIdx.x * 256 + threadIdx.x;
  if (i < n) dst[i] = f2bf(src[i]);
}

// ---------------- K1: embedding + x-part of LSTM gates ----------------
// xg[b][u][j] = emb(tw[b][u]) . W_ih[j] + b_ih[j] + b_hh[j]
__global__ __launch_bounds__(256) void k_xgate(
    const float* __restrict__ emb, const int* __restrict__ targets,
    const float* __restrict__ W_ih, const float* __restrict__ b_ih,
    const float* __restrict__ b_hh, float* __restrict__ xg)
{
  __shared__ float e_s[BB * ED];
  const int u  = blockIdx.x >> 2;
  const int jq = blockIdx.x & 3;
  const int tid = threadIdx.x;
  for (int idx = tid; idx < BB * ED; idx += 256){
    int b = idx >> 7, e = idx & 127;
    int tok = (u == 0) ? 1024 : targets[b * UU + (u - 1)];
    e_s[idx] = emb[(size_t)tok * ED + e];
  }
  __syncthreads();
  float acc[2][BB];
  #pragma unroll
  for (int r = 0; r < 2; r++)
    #pragma unroll
    for (int b = 0; b < BB; b++) acc[r][b] = 0.0f;
  const int j0 = jq * 512 + tid;
  const float* w0p = W_ih + (size_t)j0 * ED;
  const float* w1p = W_ih + (size_t)(j0 + 256) * ED;
  for (int e = 0; e < ED; e++){
    float w0 = w0p[e], w1 = w1p[e];
    #pragma unroll
    for (int b = 0; b < BB; b++){
      float ev = e_s[b * ED + e];
      acc[0][b] = fmaf(ev, w0, acc[0][b]);
      acc[1][b] = fmaf(ev, w1, acc[1][b]);
    }
  }
  #pragma unroll
  for (int r = 0; r < 2; r++){
    int j = j0 + r * 256;
    float bias = b_ih[j] + b_hh[j];
    #pragma unroll
    for (int b = 0; b < BB; b++)
      xg[((size_t)b * UP1 + u) * 2048 + j] = acc[r][b] + bias;
  }
}

// ---------------- K2: one LSTM step (chained 101x) ----------------
// 64 WGs, WG wg owns hidden units [8*wg, 8*wg+8) -> 32 gate rows.
__global__ __launch_bounds__(256) void k_lstm_step(
    const float* __restrict__ xg, const float* __restrict__ W_hh,
    float* __restrict__ pred, float* __restrict__ c_ws, int u)
{
  __shared__ float h_s[BB][520];
  __shared__ float red[32 * 257];
  __shared__ float gates_s[32][9];
  const int tid = threadIdx.x;
  const int wg  = blockIdx.x;
  const int p0  = wg * 8;
  for (int idx = tid; idx < BB * PD; idx += 256){
    int b = idx >> 9, k = idx & 511;
    h_s[b][k] = (u > 0) ? pred[((size_t)b * UP1 + (u - 1)) * PD + k] : 0.0f;
  }
  __syncthreads();
  const int jg = tid >> 5;   // 0..7, 4 gate-rows each
  const int kc = tid & 31;   // k = kc + 32*i
  float acc[4][BB];
  #pragma unroll
  for (int r = 0; r < 4; r++)
    #pragma unroll
    for (int b = 0; b < BB; b++) acc[r][b] = 0.0f;
  const float* wrow[4];
  #pragma unroll
  for (int r = 0; r < 4; r++){
    int jl = jg * 4 + r;                       // 0..31, jl = g*8 + pl
    int grow = (jl >> 3) * PD + p0 + (jl & 7); // W_hh row
    wrow[r] = W_hh + (size_t)grow * PD;
  }
  for (int i = 0; i < 16; i++){
    int k = kc + 32 * i;
    float hv[BB];
    #pragma unroll
    for (int b = 0; b < BB; b++) hv[b] = h_s[b][k];
    #pragma unroll
    for (int r = 0; r < 4; r++){
      float wv = wrow[r][k];
      #pragma unroll
      for (int b = 0; b < BB; b++) acc[r][b] = fmaf(hv[b], wv, acc[r][b]);
    }
  }
  #pragma unroll
  for (int r = 0; r < 4; r++)
    #pragma unroll
    for (int b = 0; b < BB; b++)
      red[kc * 257 + jg * 32 + r * 8 + b] = acc[r][b];
  __syncthreads();
  {
    int jl = tid >> 3, b = tid & 7;
    float s = 0.0f;
    #pragma unroll
    for (int kk = 0; kk < 32; kk++)
      s += red[kk * 257 + (jl >> 2) * 32 + (jl & 3) * 8 + b];
    gates_s[jl][b] = s;
  }
  __syncthreads();
  if (tid < 64){
    int b = tid & 7, pl = tid >> 3;
    int p = p0 + pl;
    const float* xr = xg + ((size_t)b * UP1 + u) * 2048;
    float gi = gates_s[0  + pl][b] + xr[0 * PD + p];
    float gf = gates_s[8  + pl][b] + xr[1 * PD + p];
    float gg = gates_s[16 + pl][b] + xr[2 * PD + p];
    float go = gates_s[24 + pl][b] + xr[3 * PD + p];
    float iv = sigm(gi), fv = sigm(gf), ov = sigm(go);
    float gv = tanh_fast(gg);
    float c = (u > 0) ? c_ws[b * PD + p] : 0.0f;
    c = fv * c + iv * gv;
    c_ws[b * PD + p] = c;
    pred[((size_t)b * UP1 + u) * PD + p] = ov * tanh_fast(c);
  }
}

// ---------------- K3: fp32 GEMM (A @ W^T + bias) -> bf16 out ----------------
__global__ __launch_bounds__(256) void k_gemm_bias_bf16(
    const float* __restrict__ A, const float* __restrict__ W,
    const float* __restrict__ bias, unsigned short* __restrict__ out, int M)
{
  __shared__ float a_s[16][68];
  __shared__ float b_s[16][68];
  const int m0 = blockIdx.x * 64, n0 = blockIdx.y * 64;
  const int tid = threadIdx.x;
  const int tx = tid & 15, ty = tid >> 4;
  float acc[4][4];
  #pragma unroll
  for (int i2 = 0; i2 < 4; i2++)
    #pragma unroll
    for (int j2 = 0; j2 < 4; j2++) acc[i2][j2] = 0.0f;
  for (int k0 = 0; k0 < 512; k0 += 16){
    int mm = tid >> 2, k4 = (tid & 3) * 4;
    int row = m0 + mm; if (row >= M) row = M - 1;
    float4 av = *(const float4*)(A + (size_t)row * 512 + k0 + k4);
    a_s[k4 + 0][mm] = av.x; a_s[k4 + 1][mm] = av.y;
    a_s[k4 + 2][mm] = av.z; a_s[k4 + 3][mm] = av.w;
    float4 bv = *(const float4*)(W + (size_t)(n0 + mm) * 512 + k0 + k4);
    b_s[k4 + 0][mm] = bv.x; b_s[k4 + 1][mm] = bv.y;
    b_s[k4 + 2][mm] = bv.z; b_s[k4 + 3][mm] = bv.w;
    __syncthreads();
    #pragma unroll
    for (int k = 0; k < 16; k++){
      float4 a4 = *(const float4*)&a_s[k][ty * 4];
      float4 b4 = *(const float4*)&b_s[k][tx * 4];
      float aa[4] = {a4.x, a4.y, a4.z, a4.w};
      float bb[4] = {b4.x, b4.y, b4.z, b4.w};
      #pragma unroll
      for (int i2 = 0; i2 < 4; i2++)
        #pragma unroll
        for (int j2 = 0; j2 < 4; j2++)
          acc[i2][j2] = fmaf(aa[i2], bb[j2], acc[i2][j2]);
    }
    __syncthreads();
  }
  #pragma unroll
  for (int i2 = 0; i2 < 4; i2++){
    int m = m0 + ty * 4 + i2;
    if (m < M){
      #pragma unroll
      for (int j2 = 0; j2 < 4; j2++){
        int n = n0 + tx * 4 + j2;
        out[(size_t)m * 512 + n] = f2bf(acc[i2][j2] + bias[n]);
      }
    }
  }
}

// ---------------- K4: fused joint: tanh(fe + fp) @ W_joint^T + b_joint ----------------
// grid: x = n-tile (5 of 208), y = t-tile*13 + u-tile (13x13), z = b
// block tile: M=128 (16 t x 8 u), N=208, K=512 (chunks of 32). 4 waves, each 32 rows x 208 cols.
__global__ __launch_bounds__(256) void k_joint(
    const unsigned short* __restrict__ fe, const unsigned short* __restrict__ fp,
    const unsigned short* __restrict__ wj, const float* __restrict__ bj,
    float* __restrict__ out)
{
  __shared__ unsigned short fe_s[16 * 520];
  __shared__ unsigned short fp_s[8 * 520];
  __shared__ unsigned short b_s[208 * 40];
  const int nt = blockIdx.x;
  const int tu = blockIdx.y;
  const int b  = blockIdx.z;
  const int tt = tu / 13, ut = tu - tt * 13;
  const int t0 = tt * 16, u0 = ut * 8, n0 = nt * 208;
  const int tid = threadIdx.x;
  const int w = tid >> 6, l = tid & 63;
  const int l15 = l & 15, lg = l >> 4;

  { // stage fe: 16 rows x 512 bf16 (zero-fill OOB t)
    int row = tid >> 4;
    int col = (tid & 15) * 32;
    int t = t0 + row;
    unsigned short* dst = &fe_s[row * 520 + col];
    if (t < TENC){
      const unsigned short* src = fe + ((size_t)(b * TENC + t) * 512 + col);
      ((ushort8*)dst)[0] = ((const ushort8*)src)[0];
      ((ushort8*)dst)[1] = ((const ushort8*)src)[1];
      ((ushort8*)dst)[2] = ((const ushort8*)src)[2];
      ((ushort8*)dst)[3] = ((const ushort8*)src)[3];
    } else {
      ushort8 z = {0,0,0,0,0,0,0,0};
      ((ushort8*)dst)[0] = z; ((ushort8*)dst)[1] = z;
      ((ushort8*)dst)[2] = z; ((ushort8*)dst)[3] = z;
    }
  }
  if (tid < 128){ // stage fp: 8 rows x 512 bf16 (zero-fill OOB u)
    int row = tid >> 4;
    int col = (tid & 15) * 32;
    int uu = u0 + row;
    unsigned short* dst = &fp_s[row * 520 + col];
    if (uu < UP1){
      const unsigned short* src = fp + ((size_t)(b * UP1 + uu) * 512 + col);
      ((ushort8*)dst)[0] = ((const ushort8*)src)[0];
      ((ushort8*)dst)[1] = ((const ushort8*)src)[1];
      ((ushort8*)dst)[2] = ((const ushort8*)src)[2];
      ((ushort8*)dst)[3] = ((const ushort8*)src)[3];
    } else {
      ushort8 z = {0,0,0,0,0,0,0,0};
      ((ushort8*)dst)[0] = z; ((ushort8*)dst)[1] = z;
      ((ushort8*)dst)[2] = z; ((ushort8*)dst)[3] = z;
    }
  }

  float bjv[13];
  #pragma unroll
  for (int cf = 0; cf < 13; cf++){
    int col = n0 + 16 * cf + l15;
    bjv[cf] = (col < VP1) ? bj[col] : 0.0f;
  }
  f32x4 acc[2][13];
  #pragma unroll
  for (int rg = 0; rg < 2; rg++)
    #pragma unroll
    for (int cf = 0; cf < 13; cf++)
      acc[rg][cf] = (f32x4){0.0f, 0.0f, 0.0f, 0.0f};

  for (int kc = 0; kc < 16; kc++){
    const int k0 = kc * 32;
    __syncthreads();
    if (tid < 208){ // stage B chunk: 208 rows x 32 bf16, padded stride 40
      int n = n0 + tid;
      unsigned short* dst = &b_s[tid * 40];
      if (n < VP1){
        const unsigned short* src = wj + (size_t)n * 512 + k0;
        ((ushort8*)dst)[0] = ((const ushort8*)src)[0];
        ((ushort8*)dst)[1] = ((const ushort8*)src)[1];
        ((ushort8*)dst)[2] = ((const ushort8*)src)[2];
        ((ushort8*)dst)[3] = ((const ushort8*)src)[3];
      } else {
        ushort8 z = {0,0,0,0,0,0,0,0};
        ((ushort8*)dst)[0] = z; ((ushort8*)dst)[1] = z;
        ((ushort8*)dst)[2] = z; ((ushort8*)dst)[3] = z;
      }
    }
    __syncthreads();
    // build A fragments on the fly: A[m][k] = tanh(fe[t(m)][k] + fp[u(m)][k])
    bf16x8 afr[2];
    #pragma unroll
    for (int rg = 0; rg < 2; rg++){
      int row_l = 32 * w + 16 * rg + l15;
      int ti = row_l >> 3, ui = row_l & 7;
      int koff = k0 + 8 * lg;
      ushort8 f8 = *(const ushort8*)&fe_s[ti * 520 + koff];
      ushort8 p8 = *(const ushort8*)&fp_s[ui * 520 + koff];
      ushort8 a;
      #pragma unroll
      for (int j = 0; j < 8; j++){
        float v = tanh_fast(bf2f(f8[j]) + bf2f(p8[j]));
        a[j] = f2bf(v);
      }
      afr[rg] = __builtin_bit_cast(bf16x8, a);
    }
    #pragma unroll
    for (int cf = 0; cf < 13; cf++){
      ushort8 bu = *(const ushort8*)&b_s[(16 * cf + l15) * 40 + 8 * lg];
      bf16x8 bfr = __builtin_bit_cast(bf16x8, bu);
      acc[0][cf] = __builtin_amdgcn_mfma_f32_16x16x32_bf16(afr[0], bfr, acc[0][cf], 0, 0, 0);
      acc[1][cf] = __builtin_amdgcn_mfma_f32_16x16x32_bf16(afr[1], bfr, acc[1][cf], 0, 0, 0);
    }
  }
  // epilogue: C row = (l>>4)*4 + reg within 16-row group, col = l&15
  #pragma unroll
  for (int rg = 0; rg < 2; rg++){
    #pragma unroll
    for (int cf = 0; cf < 13; cf++){
      #pragma unroll
      for (int r = 0; r < 4; r++){
        int row_l = 32 * w + 16 * rg + lg * 4 + r;
        int t = t0 + (row_l >> 3);
        int uu = u0 + (row_l & 7);
        int col = n0 + 16 * cf + l15;
        if (t < TENC && uu < UP1 && col < VP1)
          out[(((size_t)(b * TENC + t)) * UP1 + uu) * VP1 + col] = acc[rg][cf][r] + bjv[cf];
      }
    }
  }
}

extern "C" void kernel_launch(void* const* d_in, const int* in_sizes, int n_in,
                              void* d_out, int out_size, void* d_ws, size_t ws_size,
                              hipStream_t stream) {
  const float* enc_out = (const float*)d_in[0];
  const int*   targets = (const int*)d_in[1];
  // d_in[2] = target_len (unused; all == U)
  const float* emb     = (const float*)d_in[3];
  const float* W_ih    = (const float*)d_in[4];
  const float* W_hh    = (const float*)d_in[5];
  const float* b_ih    = (const float*)d_in[6];
  const float* b_hh    = (const float*)d_in[7];
  const float* W_enc   = (const float*)d_in[8];
  const float* b_enc   = (const float*)d_in[9];
  const float* W_pred  = (const float*)d_in[10];
  const float* b_pred  = (const float*)d_in[11];
  const float* W_joint = (const float*)d_in[12];
  const float* b_joint = (const float*)d_in[13];
  float* out = (float*)d_out;

  char* ws = (char*)d_ws;
  float* xg            = (float*)(ws + 0);           // 8*101*2048*4 = 6,619,136
  float* pred          = (float*)(ws + 6619136);     // 8*101*512*4  = 1,654,784
  float* c_ws          = (float*)(ws + 8273920);     // 8*512*4      = 16,384
  unsigned short* feb  = (unsigned short*)(ws + 8290304);   // 1600*512*2 = 1,638,400
  unsigned short* fpb  = (unsigned short*)(ws + 9928704);   // 808*512*2  = 827,392
  unsigned short* wjb  = (unsigned short*)(ws + 10756096);  // 1025*512*2 = 1,049,600
  // total ~11.8 MB

  hipLaunchKernelGGL(k_cvt_bf16, dim3((VP1 * 512 + 255) / 256), dim3(256), 0, stream,
                     W_joint, wjb, VP1 * 512);
  hipLaunchKernelGGL(k_xgate, dim3(404), dim3(256), 0, stream,
                     emb, targets, W_ih, b_ih, b_hh, xg);
  hipLaunchKernelGGL(k_gemm_bias_bf16, dim3(25, 8), dim3(256), 0, stream,
                     enc_out, W_enc, b_enc, feb, 1600);
  for (int u = 0; u < UP1; u++)
    hipLaunchKernelGGL(k_lstm_step, dim3(64), dim3(256), 0, stream,
                       xg, W_hh, pred, c_ws, u);
  hipLaunchKernelGGL(k_gemm_bias_bf16, dim3(13, 8), dim3(256), 0, stream,
                     pred, W_pred, b_pred, fpb, 808);
  hipLaunchKernelGGL(k_joint, dim3(5, 169, 8), dim3(256), 0, stream,
                     feb, fpb, wjb, b_joint, out);
}